// Round 4
// baseline (96.785 us; speedup 1.0000x reference)
//
#include <hip/hip_runtime.h>
#include <math.h>

// Problem constants (from reference): w=0.05, b=5.803, single species.
#define NBINS_MAX 512
#define NMAX      1024                 // atom capacity for LDS staging
#define NPAIR_CAP 256                  // u64 bin-pair accumulator capacity
#define NSLOT     16                   // u64 slots per bin-pair
constexpr float KW       = 0.05f;
constexpr float INV_KW   = 20.0f;      // 1/w
constexpr float GNORM    = 0.3989422804014327f * INV_KW; // 1/(w*sqrt(2pi))
constexpr float COEFF    = 0.33674809f;    // b*b*0.01
constexpr float FOUR_PI  = 12.566370614359172f;
constexpr float W5       = 5.0f * KW;  // direct-KDE window +-5 sigma
constexpr float QSCALE     = 1048576.0f;   // 2^20 fixed point for block flush
constexpr float INV_QSCALE = 1.0f / QSCALE;
#define SENT64  (NPAIR_CAP * NSLOT)    // u64 sentinel index (untouched poison)

// R16: single-kernel direct-KDE, v4 -- latency-chain removal.
// R15 post-mortem (40.6us, VALUBusy 8.9%, Occ 13.7%): window decomposes as
// ~22us all-blocks-stalled + ~18us one-block tail. Diagnosed chains:
//  (a) tail S(Q) loop: per-iter ds_read -> lgkmcnt(0) -> use, ~120cyc x400
//      serial with only 2 waves/SIMD to hide it (~18us).
//  (b) scatter inner loop: per-lane ds_read sh_r[k]; compiler's lgkmcnt(0)
//      before its use also drains the previous ds_add -> serialized LDS
//      round-trip per KDE bin; plus 3.4M v_exp on the 1/4-rate trans pipe.
//  (c) flush: 102k uncoalesced 32B-sector device atomics (WRITE_SIZE
//      2.9MB = 102k x 32B confirms) + per-wave vmcnt(0) drain.
// Fixes:
//  (a) float2-packed (weight,r) LDS + unroll-8 + 4 accumulators: 8
//      independent ds_read_b64 in flight -> latency amortized 8x.
//  (b) Gaussian ratio recurrence: e_{k+1}=e_k*g, g_{k+1}=g*m with
//      m=exp(-du^2), du=dr/w. 2 muls/bin + 2 exps/pair replaces per-bin
//      {ds_read + exp}. r_k = fmaf(k,dr,r0) (<=1 ulp vs linspace; G err
//      <4e-6). Rounding: 23 muls ~ 1.4e-6 relative -- fine vs absmax.
//  (c) u64-packed atomics: 2 bins/atomic (fields <= 3.5e8 << 2^32, no
//      cross-field carry; NSLOT=16 -> 16 blocks/slot, 12x margin) ->
//      51k atomics, half the drain and half the tail loads.
// Numerics otherwise identical to R15 (absmax 1.5e-5): exact f32 LDS KDE
// accumulation; one 2^20 quantization per block per bin; poison handled by
// uniform-poison + unsigned wrap vs untouched sentinel words (R12 trick).

__global__ void __launch_bounds__(512)
fused_kernel(const float* __restrict__ pos,
             const float* __restrict__ cell,
             const float* __restrict__ rbins,
             const float* __restrict__ qbins,
             unsigned long long* __restrict__ slots, // [NPAIR_CAP*NSLOT] +sent64+ticket
             float*        __restrict__ out,
             int N, int nbins)
{
    __shared__ float  sh_pos[3 * NMAX];    // xyz-interleaved positions
    __shared__ float  sh_hist[NBINS_MAX];  // KDE accumulator
    __shared__ float  sh_r[NBINS_MAX];     // exact r_bins (parity with reference)
    __shared__ float2 sh_w2[NBINS_MAX];    // tail: {trapz*r*G, r}
    __shared__ unsigned int sh_last;
    const int t  = threadIdx.x;
    const int nb = blockDim.x;             // 512

    // --- stage positions (float4-vectorized), rbins, zero hist ---
    const int nflt = 3 * N;
    const int nvec = nflt >> 2;
    const float4* p4 = (const float4*)pos;
    for (int v = t; v < nvec; v += nb) {
        const float4 x = p4[v];
        sh_pos[4*v + 0] = x.x;
        sh_pos[4*v + 1] = x.y;
        sh_pos[4*v + 2] = x.z;
        sh_pos[4*v + 3] = x.w;
    }
    for (int s = (nvec << 2) + t; s < nflt; s += nb)
        sh_pos[s] = pos[s];                // tail (absent for N=1024)
    for (int k = t; k < nbins; k += nb) {
        sh_r[k]    = rbins[k];
        sh_hist[k] = 0.0f;
    }

    // cell and its inverse (wave-uniform, all threads compute)
    float cm[9];
#pragma unroll
    for (int k = 0; k < 9; ++k) cm[k] = cell[k];
    const float a00 = cm[0], a01 = cm[1], a02 = cm[2];
    const float a10 = cm[3], a11 = cm[4], a12 = cm[5];
    const float a20 = cm[6], a21 = cm[7], a22 = cm[8];
    const float det = a00*(a11*a22 - a12*a21)
                    - a01*(a10*a22 - a12*a20)
                    + a02*(a10*a21 - a11*a20);
    const float id = 1.0f / det;
    float im[9];
    im[0] = (a11*a22 - a12*a21)*id;
    im[1] = (a02*a21 - a01*a22)*id;
    im[2] = (a01*a12 - a02*a11)*id;
    im[3] = (a12*a20 - a10*a22)*id;
    im[4] = (a00*a22 - a02*a20)*id;
    im[5] = (a02*a10 - a00*a12)*id;
    im[6] = (a10*a21 - a11*a20)*id;
    im[7] = (a01*a20 - a00*a21)*id;
    im[8] = (a00*a11 - a01*a10)*id;

    const float r0     = rbins[0];
    const float rend   = rbins[nbins - 1];
    const float minb   = r0   - 3.0f * KW;   // reference's in_win gate
    const float maxb   = rend + 3.0f * KW;
    const float dr     = (rend - r0) / (float)(nbins - 1);   // linspace spacing
    const float inv_dr = 1.0f / dr;
    const int   WB     = (int)(W5 * inv_dr) + 1;  // half-window in bins (~11)
    const float du     = dr * INV_KW;             // u-step per bin (~0.496)
    const float hdu2   = 0.5f * du * du;
    const float m2     = __expf(-du * du);        // recurrence ratio-of-ratio

    __syncthreads();

    // --- scatter: TWO row-pairs per block (256 blocks, perfect balance) ---
    const int nrp = (N + 1) / 2;
    const int rp0 = 2 * blockIdx.x;

    auto do_rowpair = [&](int rp) {
        const int A    = rp;
        const int B    = N - 1 - rp;
        const int cntA = N - 1 - A;
        const int cntB = (B != A) ? A : 0;   // guard odd-N center row
        const int tot  = cntA + cntB;
        for (int p = t; p < tot; p += nb) {
            int i, j;
            if (p < cntA) { i = A; j = A + 1 + p; }
            else          { i = B; j = B + 1 + (p - cntA); }

            const float dx = sh_pos[3*j + 0] - sh_pos[3*i + 0];
            const float dy = sh_pos[3*j + 1] - sh_pos[3*i + 1];
            const float dz = sh_pos[3*j + 2] - sh_pos[3*i + 2];
            float fx = dx*im[0] + dy*im[3] + dz*im[6];
            float fy = dx*im[1] + dy*im[4] + dz*im[7];
            float fz = dx*im[2] + dy*im[5] + dz*im[8];
            fx -= rintf(fx); fy -= rintf(fy); fz -= rintf(fz);   // min image
            const float mx = fx*cm[0] + fy*cm[3] + fz*cm[6];
            const float my = fx*cm[1] + fy*cm[4] + fz*cm[7];
            const float mz = fx*cm[2] + fy*cm[5] + fz*cm[8];
            const float d  = sqrtf(mx*mx + my*my + mz*mz + 1e-10f);

            if (d > minb && d < maxb) {
                const int kc  = (int)((d - r0) * inv_dr);
                int klo = kc - WB; if (klo < 0)         klo = 0;
                int khi = kc + WB; if (khi > nbins - 1) khi = nbins - 1;
                // Gaussian ratio recurrence: no LDS reads, 2 exps total.
                const float rlo = fmaf((float)klo, dr, r0);  // == sh_r[klo] +-1ulp
                const float u0  = (rlo - d) * INV_KW;
                float e = __expf(-0.5f * u0 * u0);
                float g = __expf(-(u0 * du + hdu2));
                for (int k = klo; k <= khi; ++k) {
                    atomicAdd(&sh_hist[k], e);   // ds_add_f32, fire-and-forget
                    e *= g;
                    g *= m2;
                }
            }
        }
    };
    do_rowpair(rp0);
    if (rp0 + 1 < nrp) do_rowpair(rp0 + 1);

    // --- flush: u64-packed fixed-point atomics, 2 bins per op ---
    __syncthreads();
    const int npair = (nbins + 1) >> 1;
    const int slot  = blockIdx.x & (NSLOT - 1);
    for (int bp = t; bp < npair; bp += nb) {
        const int   k0 = 2 * bp;
        const float v0 = sh_hist[k0];
        const float v1 = (k0 + 1 < nbins) ? sh_hist[k0 + 1] : 0.0f;
        const unsigned int q0 = (unsigned int)rintf(v0 * QSCALE);
        const unsigned int q1 = (unsigned int)rintf(v1 * QSCALE);
        const unsigned long long val =
            (unsigned long long)q0 | ((unsigned long long)q1 << 32);
        if (val) atomicAdd(&slots[bp * NSLOT + slot], val);  // global_atomic_add_x2
    }
    // Hand-rolled RELEASE: wait my wave's no-return atomics acked at the
    // coherent point. NO buffer_wbl2/buffer_inv (R14's 65us lesson).
    asm volatile("s_waitcnt vmcnt(0)" ::: "memory");
    __syncthreads();                       // all waves acked before t0 proceeds
    unsigned int* w32 = (unsigned int*)slots;
    if (t == 0) {
        const unsigned int old = __hip_atomic_fetch_add(
            &w32[2 * SENT64 + 2], 1u,
            __ATOMIC_RELAXED, __HIP_MEMORY_SCOPE_AGENT);   // ticket (relaxed)
        const unsigned int tb  = __hip_atomic_load(
            &w32[2 * SENT64 + 3],
            __ATOMIC_RELAXED, __HIP_MEMORY_SCOPE_AGENT);   // untouched poison word
        sh_last = ((old - tb) == (unsigned int)(gridDim.x - 1)) ? 1u : 0u;
    }
    __syncthreads();
    if (!sh_last) return;                  // all non-last blocks exit here

    // --- tail (one block): parallel coalesced slot reads -> G(r) + weights ---
    const unsigned long long base64 = __hip_atomic_load(
        &slots[SENT64], __ATOMIC_RELAXED, __HIP_MEMORY_SCOPE_AGENT);
    const float vol     = fabsf(det);
    const float n_pairs = 0.5f * (float)N * (float)(N - 1);
    const float rho     = (float)N / vol;
    const float pref    = (vol / n_pairs) * GNORM;

    for (int bp = t; bp < npair; bp += nb) {
        unsigned long long lo = 0, hi = 0;
#pragma unroll
        for (int s = 0; s < NSLOT; ++s) {     // 16 independent loads in flight
            const unsigned long long dv = __hip_atomic_load(
                &slots[bp * NSLOT + s],
                __ATOMIC_RELAXED, __HIP_MEMORY_SCOPE_AGENT) - base64;
            lo += (unsigned long long)(unsigned int)dv;
            hi += (unsigned long long)(unsigned int)(dv >> 32);
        }
        const int k0 = 2 * bp;
        {
            const float summed = (float)lo * INV_QSCALE;
            const float rk = sh_r[k0];
            const float g  = pref * summed / (FOUR_PI * rk * rk);
            const float G  = COEFF * (g - 1.0f);
            out[k0] = G;
            const float w_lo = (k0 > 0)         ? (rk - sh_r[k0 - 1]) : 0.0f;
            const float w_hi = (k0 < nbins - 1) ? (sh_r[k0 + 1] - rk) : 0.0f;
            sh_w2[k0] = make_float2(0.5f * (w_lo + w_hi) * rk * G, rk);
        }
        if (k0 + 1 < nbins) {
            const int k1 = k0 + 1;
            const float summed = (float)hi * INV_QSCALE;
            const float rk = sh_r[k1];
            const float g  = pref * summed / (FOUR_PI * rk * rk);
            const float G  = COEFF * (g - 1.0f);
            out[k1] = G;
            const float w_lo = (rk - sh_r[k1 - 1]);
            const float w_hi = (k1 < nbins - 1) ? (sh_r[k1 + 1] - rk) : 0.0f;
            sh_w2[k1] = make_float2(0.5f * (w_lo + w_hi) * rk * G, rk);
        }
    }
    __syncthreads();

    // --- S(Q), F(Q): one q per thread; unroll-8, 4 accumulators (latency) ---
    const int ng = nbins & ~7;
    for (int qi = t; qi < nbins; qi += nb) {
        const float q    = qbins[qi];
        const float qinv = 1.0f / (q + 1e-10f);
        float a0 = 0.0f, a1 = 0.0f, a2 = 0.0f, a3 = 0.0f;
        int k = 0;
        for (; k < ng; k += 8) {             // 8 ds_read_b64 in flight per group
            const float2 v0 = sh_w2[k+0]; const float2 v1 = sh_w2[k+1];
            const float2 v2 = sh_w2[k+2]; const float2 v3 = sh_w2[k+3];
            const float2 v4 = sh_w2[k+4]; const float2 v5 = sh_w2[k+5];
            const float2 v6 = sh_w2[k+6]; const float2 v7 = sh_w2[k+7];
            a0 += v0.x * __sinf(q * v0.y) + v4.x * __sinf(q * v4.y);
            a1 += v1.x * __sinf(q * v1.y) + v5.x * __sinf(q * v5.y);
            a2 += v2.x * __sinf(q * v2.y) + v6.x * __sinf(q * v6.y);
            a3 += v3.x * __sinf(q * v3.y) + v7.x * __sinf(q * v7.y);
        }
        for (; k < nbins; ++k) {
            const float2 v = sh_w2[k];
            a0 += v.x * __sinf(q * v.y);
        }
        const float S = 1.0f + FOUR_PI * rho * ((a0 + a1) + (a2 + a3)) * qinv;
        out[nbins + qi]     = S;               // S(Q)
        out[2 * nbins + qi] = q * (S - 1.0f);  // F(Q)
    }
}

// ---------------------------------------------------------------------------
extern "C" void kernel_launch(void* const* d_in, const int* in_sizes, int n_in,
                              void* d_out, int out_size, void* d_ws, size_t ws_size,
                              hipStream_t stream)
{
    const float* pos   = (const float*)d_in[0];  // (N,3) f32
    const float* cell  = (const float*)d_in[1];  // (3,3) f32
    const float* rbins = (const float*)d_in[2];  // (nbins,) f32
    const float* qbins = (const float*)d_in[3];  // (nbins,) f32
    float* out = (float*)d_out;                  // (3, nbins) f32

    const int N     = in_sizes[0] / 3;
    const int nbins = in_sizes[2];
    const int nrp   = (N + 1) / 2;               // row-pairs
    const int grid  = (nrp + 1) / 2;             // 2 row-pairs per block -> 256

    unsigned long long* slots = (unsigned long long*)d_ws;

    hipLaunchKernelGGL(fused_kernel, dim3(grid), dim3(512), 0, stream,
                       pos, cell, rbins, qbins, slots, out, N, nbins);
}

// Round 5
// 83.466 us; speedup vs baseline: 1.1596x; 1.1596x over previous
//
#include <hip/hip_runtime.h>
#include <math.h>

// Problem constants (from reference): w=0.05, b=5.803, single species.
#define NBINS_MAX 512
#define NMAX      1024                 // atom capacity for LDS staging
#define NSLOT     8                    // u32 slots per bin (32 blocks/slot)
constexpr float KW       = 0.05f;
constexpr float INV_KW   = 20.0f;      // 1/w
constexpr float GNORM    = 0.3989422804014327f * INV_KW; // 1/(w*sqrt(2pi))
constexpr float COEFF    = 0.33674809f;    // b*b*0.01
constexpr float FOUR_PI  = 12.566370614359172f;
constexpr float W5       = 5.0f * KW;  // direct-KDE window +-5 sigma
constexpr float QSCALE     = 1048576.0f;   // 2^20 fixed point for block flush
constexpr float INV_QSCALE = 1.0f / QSCALE;
#define SENT32  (NBINS_MAX * NSLOT)    // u32 sentinel index (untouched poison)

// R17: TWO kernels, ZERO in-kernel synchronization.
// R16 post-mortem: all three R16 fixes landed per counters (bank conflicts
// 240k->4.5k, WRITE_SIZE halved, exps cut 10x) yet dur unchanged 40.6->42.4us
// -> the diagnosed chains were NOT the bottleneck. Hard external datum: R12's
// THREE-kernel pipeline = 75.3us total = 39.3 fill + ~36us for 3 kernels AND
// 3 launch gaps -- less than the fused kernel alone. Every fused variant
// (R13-R16) lost to R12. The structural element R12 lacks: per-wave vmcnt(0)
// drain + single-address ticket + one-block tail gated on device-scope
// visibility. Eliminate it:
//   K1: scatter + LDS-KDE (R16 recurrence) + fire-and-forget u32 slot
//       atomics; waves retire with no waits (R12-proven pattern).
//   K2: dispatch boundary IS the sync (kernel-end flush / kernel-start
//       invalidate). 400 blocks; each block REDUNDANTLY rebuilds G from the
//       12.8KB slot array with plain coalesced uint4 loads (L2-hot, ~1us)
//       -- 400x redundancy of a trivial reduction buys zero grid sync --
//       then computes S,F for its own q (R12-K3 reduce pattern).
// Also reverts R16's u64 2-bin packing (low->high carry vs poison base
// doubled absmax); u32 slots are exact mod 2^32: value = slot - sentinel
// (unsigned wrap), per-slot true sum < 2^32 (32 blocks x ~2.2e7 ~ 7e8).
// Ablation value: K1 now contains ONLY scatter+LDS+flush. K1 ~ 8us =>
// fused mystery was the ticket structure; K1 ~ 35us => scatter path itself.

__global__ void __launch_bounds__(512)
scatter_kernel(const float* __restrict__ pos,
               const float* __restrict__ cell,
               const float* __restrict__ rbins,
               unsigned int* __restrict__ slots,  // [NBINS_MAX*NSLOT] + sentinel
               int N, int nbins)
{
    __shared__ float sh_pos[3 * NMAX];     // xyz-interleaved positions
    __shared__ float sh_hist[NBINS_MAX];   // KDE accumulator
    const int t  = threadIdx.x;
    const int nb = blockDim.x;             // 512

    // --- stage positions (float4-vectorized), zero hist ---
    const int nflt = 3 * N;
    const int nvec = nflt >> 2;
    const float4* p4 = (const float4*)pos;
    for (int v = t; v < nvec; v += nb) {
        const float4 x = p4[v];
        sh_pos[4*v + 0] = x.x;
        sh_pos[4*v + 1] = x.y;
        sh_pos[4*v + 2] = x.z;
        sh_pos[4*v + 3] = x.w;
    }
    for (int s = (nvec << 2) + t; s < nflt; s += nb)
        sh_pos[s] = pos[s];                // tail (absent for N=1024)
    for (int k = t; k < nbins; k += nb)
        sh_hist[k] = 0.0f;

    // cell and its inverse (wave-uniform, all threads compute)
    float cm[9];
#pragma unroll
    for (int k = 0; k < 9; ++k) cm[k] = cell[k];
    const float a00 = cm[0], a01 = cm[1], a02 = cm[2];
    const float a10 = cm[3], a11 = cm[4], a12 = cm[5];
    const float a20 = cm[6], a21 = cm[7], a22 = cm[8];
    const float det = a00*(a11*a22 - a12*a21)
                    - a01*(a10*a22 - a12*a20)
                    + a02*(a10*a21 - a11*a20);
    const float id = 1.0f / det;
    float im[9];
    im[0] = (a11*a22 - a12*a21)*id;
    im[1] = (a02*a21 - a01*a22)*id;
    im[2] = (a01*a12 - a02*a11)*id;
    im[3] = (a12*a20 - a10*a22)*id;
    im[4] = (a00*a22 - a02*a20)*id;
    im[5] = (a02*a10 - a00*a12)*id;
    im[6] = (a10*a21 - a11*a20)*id;
    im[7] = (a01*a20 - a00*a21)*id;
    im[8] = (a00*a11 - a01*a10)*id;

    const float r0     = rbins[0];
    const float rend   = rbins[nbins - 1];
    const float minb   = r0   - 3.0f * KW;   // reference's in_win gate
    const float maxb   = rend + 3.0f * KW;
    const float dr     = (rend - r0) / (float)(nbins - 1);   // linspace spacing
    const float inv_dr = 1.0f / dr;
    const int   WB     = (int)(W5 * inv_dr) + 1;  // half-window in bins (~11)
    const float du     = dr * INV_KW;             // u-step per bin (~0.496)
    const float hdu2   = 0.5f * du * du;
    const float m2     = __expf(-du * du);        // recurrence ratio-of-ratio

    __syncthreads();

    // --- scatter: TWO row-pairs per block (256 blocks, perfect balance) ---
    const int nrp = (N + 1) / 2;
    const int rp0 = 2 * blockIdx.x;

    auto do_rowpair = [&](int rp) {
        const int A    = rp;
        const int B    = N - 1 - rp;
        const int cntA = N - 1 - A;
        const int cntB = (B != A) ? A : 0;   // guard odd-N center row
        const int tot  = cntA + cntB;
        for (int p = t; p < tot; p += nb) {
            int i, j;
            if (p < cntA) { i = A; j = A + 1 + p; }
            else          { i = B; j = B + 1 + (p - cntA); }

            const float dx = sh_pos[3*j + 0] - sh_pos[3*i + 0];
            const float dy = sh_pos[3*j + 1] - sh_pos[3*i + 1];
            const float dz = sh_pos[3*j + 2] - sh_pos[3*i + 2];
            float fx = dx*im[0] + dy*im[3] + dz*im[6];
            float fy = dx*im[1] + dy*im[4] + dz*im[7];
            float fz = dx*im[2] + dy*im[5] + dz*im[8];
            fx -= rintf(fx); fy -= rintf(fy); fz -= rintf(fz);   // min image
            const float mx = fx*cm[0] + fy*cm[3] + fz*cm[6];
            const float my = fx*cm[1] + fy*cm[4] + fz*cm[7];
            const float mz = fx*cm[2] + fy*cm[5] + fz*cm[8];
            const float d  = sqrtf(mx*mx + my*my + mz*mz + 1e-10f);

            if (d > minb && d < maxb) {
                const int kc  = (int)((d - r0) * inv_dr);
                int klo = kc - WB; if (klo < 0)         klo = 0;
                int khi = kc + WB; if (khi > nbins - 1) khi = nbins - 1;
                // Gaussian ratio recurrence: no LDS reads, 2 exps per pair.
                const float rlo = fmaf((float)klo, dr, r0);  // == rbins[klo] +-1ulp
                const float u0  = (rlo - d) * INV_KW;
                float e = __expf(-0.5f * u0 * u0);
                float g = __expf(-(u0 * du + hdu2));
                for (int k = klo; k <= khi; ++k) {
                    atomicAdd(&sh_hist[k], e);   // ds_add_f32, fire-and-forget
                    e *= g;
                    g *= m2;
                }
            }
        }
    };
    do_rowpair(rp0);
    if (rp0 + 1 < nrp) do_rowpair(rp0 + 1);

    // --- flush: u32 fixed-point atomics, fire-and-forget; waves then END ---
    __syncthreads();
    const int slot = blockIdx.x & (NSLOT - 1);
    for (int k = t; k < nbins; k += nb) {
        const unsigned int q = (unsigned int)rintf(sh_hist[k] * QSCALE);
        if (q) atomicAdd(&slots[k * NSLOT + slot], q);  // device-scope
    }
    // NO vmcnt wait, NO ticket, NO tail. Kernel-end drain overlaps the
    // K2 launch gap exactly as in R12's proven 3-kernel pipeline.
}

// ---------------------------------------------------------------------------
// K2: every block redundantly rebuilds G (cheap), computes S,F for its q.
// Dispatch boundary guarantees slot visibility -> PLAIN coalesced loads.
// ---------------------------------------------------------------------------
__global__ void __launch_bounds__(256)
spectrum_kernel(const unsigned int* __restrict__ slots,
                const float* __restrict__ cell,
                const float* __restrict__ rbins,
                const float* __restrict__ qbins,
                float* __restrict__ out,
                int N, int nbins)
{
    __shared__ float  sh_r[NBINS_MAX];     // exact r_bins (parity with reference)
    __shared__ float2 sh_w2[NBINS_MAX];    // {G -> trapz*r*G, r}
    __shared__ float  sh_red[4];
    const int t = threadIdx.x;

    const unsigned int base = slots[SENT32];   // untouched poison word

    // cell det (wave-uniform)
    const float a00 = cell[0], a01 = cell[1], a02 = cell[2];
    const float a10 = cell[3], a11 = cell[4], a12 = cell[5];
    const float a20 = cell[6], a21 = cell[7], a22 = cell[8];
    const float det = a00*(a11*a22 - a12*a21)
                    - a01*(a10*a22 - a12*a20)
                    + a02*(a10*a21 - a11*a20);
    const float vol     = fabsf(det);
    const float n_pairs = 0.5f * (float)N * (float)(N - 1);
    const float rho     = (float)N / vol;
    const float pref    = (vol / n_pairs) * GNORM;

    // --- pass 1: slots -> G (each block redundantly; 2 uint4 loads/bin) ---
    const uint4* s4 = (const uint4*)slots;
    for (int k = t; k < nbins; k += 256) {
        const uint4 aa = s4[2*k + 0];
        const uint4 bb = s4[2*k + 1];
        unsigned long long tot = 0;                  // exact: per-slot < 2^32
        tot += (unsigned long long)(aa.x - base);    // unsigned wrap vs poison
        tot += (unsigned long long)(aa.y - base);
        tot += (unsigned long long)(aa.z - base);
        tot += (unsigned long long)(aa.w - base);
        tot += (unsigned long long)(bb.x - base);
        tot += (unsigned long long)(bb.y - base);
        tot += (unsigned long long)(bb.z - base);
        tot += (unsigned long long)(bb.w - base);
        const float summed = (float)tot * INV_QSCALE;
        const float rk = rbins[k];
        const float g  = pref * summed / (FOUR_PI * rk * rk);
        const float G  = COEFF * (g - 1.0f);
        if (blockIdx.x == 0) out[k] = G;             // single writer for G(r)
        sh_r[k]  = rk;
        sh_w2[k] = make_float2(G, rk);
    }
    __syncthreads();

    // --- pass 2: G -> trapezoid weight * r * G (needs neighbor r) ---
    for (int k = t; k < nbins; k += 256) {
        const float rk   = sh_r[k];
        const float w_lo = (k > 0)         ? (rk - sh_r[k - 1]) : 0.0f;
        const float w_hi = (k < nbins - 1) ? (sh_r[k + 1] - rk) : 0.0f;
        sh_w2[k].x = 0.5f * (w_lo + w_hi) * rk * sh_w2[k].x;
    }
    __syncthreads();

    // --- S(Q), F(Q) for q = qbins[blockIdx.x]: 400-term LDS-hot reduce ---
    const int   qi   = blockIdx.x;
    const float q    = qbins[qi];
    const float qinv = 1.0f / (q + 1e-10f);
    float acc = 0.0f;
    for (int k = t; k < nbins; k += 256) {
        const float2 v = sh_w2[k];
        acc += v.x * __sinf(q * v.y);
    }
#pragma unroll
    for (int off = 32; off > 0; off >>= 1)
        acc += __shfl_down(acc, off, 64);
    if ((t & 63) == 0) sh_red[t >> 6] = acc;
    __syncthreads();
    if (t == 0) {
        const float S = 1.0f + FOUR_PI * rho * qinv *
                        (sh_red[0] + sh_red[1] + sh_red[2] + sh_red[3]);
        out[nbins + qi]     = S;               // S(Q)
        out[2 * nbins + qi] = q * (S - 1.0f);  // F(Q)
    }
}

// ---------------------------------------------------------------------------
extern "C" void kernel_launch(void* const* d_in, const int* in_sizes, int n_in,
                              void* d_out, int out_size, void* d_ws, size_t ws_size,
                              hipStream_t stream)
{
    const float* pos   = (const float*)d_in[0];  // (N,3) f32
    const float* cell  = (const float*)d_in[1];  // (3,3) f32
    const float* rbins = (const float*)d_in[2];  // (nbins,) f32
    const float* qbins = (const float*)d_in[3];  // (nbins,) f32
    float* out = (float*)d_out;                  // (3, nbins) f32

    const int N     = in_sizes[0] / 3;
    const int nbins = in_sizes[2];
    const int nrp   = (N + 1) / 2;               // row-pairs
    const int grid1 = (nrp + 1) / 2;             // 2 row-pairs per block -> 256

    unsigned int* slots = (unsigned int*)d_ws;   // [NBINS_MAX*NSLOT] + sentinel

    hipLaunchKernelGGL(scatter_kernel, dim3(grid1), dim3(512), 0, stream,
                       pos, cell, rbins, slots, N, nbins);
    hipLaunchKernelGGL(spectrum_kernel, dim3(nbins), dim3(256), 0, stream,
                       slots, cell, rbins, qbins, out, N, nbins);
}